// Round 7
// baseline (164.208 us; speedup 1.0000x reference)
//
#include <hip/hip_runtime.h>

namespace {
constexpr int Bx = 8, Cc = 64, Hh = 128, Ww = 128, Co = 64;
constexpr int Ll = Hh * Ww;        // 16384 = 2^14
constexpr int NPIX = Bx * Ll;      // 131072
constexpr int TP = 64;             // pixels per block in k23
}

using short8 = __attribute__((ext_vector_type(8))) short;
using f32x4  = __attribute__((ext_vector_type(4))) float;

__device__ __forceinline__ unsigned short f32_to_bf16(float f) {
    union { float f; unsigned u; } un; un.f = f;
    unsigned r = un.u + 0x7FFFu + ((un.u >> 16) & 1u);   // round-to-nearest-even
    return (unsigned short)(r >> 16);
}
__device__ __forceinline__ float bf16_to_f32(unsigned short h) {
    union { unsigned u; float f; } un; un.u = (unsigned)h << 16; return un.f;
}

// ---------------- k0: pack weights ----------------
// wt16 [c][16] fp32: gate(4) + geom(12) — consumed by k1's scalar path.
// vwhi/vwlo: value_w as MFMA A-frags (hi/lo bf16), [t=4][ks=2][lane=64][jj=8]:
//   A row = t*16+(lane&15) = value out channel, k = ks*32+(lane>>4)*8+jj = c.
// pwb16 k-order m' = c*4+r (matches k23's packed agg writes).
__global__ __launch_bounds__(256) void k0_pack_weights(
    const float* __restrict__ gate_w,   // [4][64]
    const float* __restrict__ geom_w,   // [12][64]
    const float* __restrict__ value_w,  // [64][64]
    const float* __restrict__ pw_w,     // [64][256], m = r*64+c
    float* __restrict__ wt16,           // [64][16]
    unsigned short* __restrict__ vwhi,  // [4096]
    unsigned short* __restrict__ vwlo,  // [4096]
    unsigned short* __restrict__ pwb16) // [64][256] bf16, m' = c*4+r
{
    for (int idx = threadIdx.x; idx < Cc * 16; idx += 256) {
        const int c = idx >> 4, j = idx & 15;
        wt16[idx] = (j < 4) ? gate_w[j * Cc + c] : geom_w[(j - 4) * Cc + c];
    }
    for (int flat = threadIdx.x; flat < 4096; flat += 256) {
        const int t    = flat >> 10;
        const int ks   = (flat >> 9) & 1;
        const int lane = (flat >> 3) & 63;
        const int jj   = flat & 7;
        const int j = t * 16 + (lane & 15);
        const int c = ks * 32 + ((lane >> 4) & 3) * 8 + jj;
        const float val = value_w[j * Cc + c];
        const unsigned short h = f32_to_bf16(val);
        vwhi[flat] = h;
        vwlo[flat] = f32_to_bf16(val - bf16_to_f32(h));
    }
    for (int idx = threadIdx.x; idx < Co * 256; idx += 256) {
        const int o = idx >> 8, m = idx & 255;
        const int r = m >> 6, c = m & 63;
        pwb16[o * 256 + c * 4 + r] = f32_to_bf16(pw_w[idx]);
    }
}

__device__ __forceinline__ float softplusf(float v) {
    return v > 20.f ? v : log1pf(__expf(v));
}

// ---------------- k1: hybrid projections ----------------
// Per 256-px block: thread tid stages pixel l0+tid's 64 x values into LDS as
// bf16 hi/lo AND accumulates the 16 gate/geom outputs in fp32 scalar FMA
// (the theta->half-angle path is chaotically sensitive where |(c2,s2)| ~ 0,
// so geometry must match the fp32 reference to ~1e-7; bf16 MFMA there fails).
// Value channels (error-tolerant: bf16-rounded downstream) via hi/lo MFMA:
// wave w owns px-tiles w*4..+3, 4 j-tiles x 6 MFMAs, v stored fp32 pixel-major.
__global__ __launch_bounds__(256) void k1_project(
    const float* __restrict__ x,       // [B][64][L]
    const unsigned short* __restrict__ vwhi,
    const unsigned short* __restrict__ vwlo,
    const float* __restrict__ wt16,    // [64][16]
    const float* __restrict__ gate_b,  // [4]
    const float* __restrict__ geom_b,  // [12]
    float* __restrict__ v,             // [B][L][64]  (pixel-major)
    float* __restrict__ mu,            // [B][4][L]
    float* __restrict__ cs2, float* __restrict__ sn2,
    float* __restrict__ bse, float* __restrict__ hyp)  // each [B][4][L]
{
    __shared__ unsigned short xhi[256][72];   // 36 KB
    __shared__ unsigned short xlo[256][72];   // 36 KB

    const int tid  = threadIdx.x;
    const int lane = tid & 63;
    const int w    = tid >> 6;
    const int pix0 = blockIdx.x * 256;
    const int b    = pix0 >> 14;
    const int l0   = pix0 & (Ll - 1);

    // stage X -> LDS bf16 hi/lo + fp32 scalar gate/geom accumulation
    float acc[16];
#pragma unroll
    for (int j = 0; j < 16; ++j) acc[j] = 0.f;

    const float* xb = x + (size_t)b * Cc * Ll + (l0 + tid);
#pragma unroll
    for (int c0 = 0; c0 < 64; c0 += 8) {
        float xv[8];
#pragma unroll
        for (int j = 0; j < 8; ++j) xv[j] = xb[(size_t)(c0 + j) * Ll];
        uint4 ph, pl;
        unsigned* hp = (unsigned*)&ph;
        unsigned* lp = (unsigned*)&pl;
#pragma unroll
        for (int j = 0; j < 4; ++j) {
            const unsigned short h0 = f32_to_bf16(xv[2 * j]);
            const unsigned short h1 = f32_to_bf16(xv[2 * j + 1]);
            hp[j] = (unsigned)h0 | ((unsigned)h1 << 16);
            const unsigned short e0 = f32_to_bf16(xv[2 * j]     - bf16_to_f32(h0));
            const unsigned short e1 = f32_to_bf16(xv[2 * j + 1] - bf16_to_f32(h1));
            lp[j] = (unsigned)e0 | ((unsigned)e1 << 16);
        }
        *(uint4*)&xhi[tid][c0] = ph;
        *(uint4*)&xlo[tid][c0] = pl;
#pragma unroll
        for (int j = 0; j < 8; ++j) {
            const float* wr = wt16 + (c0 + j) * 16;   // uniform -> s_load
#pragma unroll
            for (int jj = 0; jj < 16; ++jj) acc[jj] = fmaf(wr[jj], xv[j], acc[jj]);
        }
    }

    // A fragments (value weights; global, independent of LDS) before barrier
    short8 afh[8], afl[8];
#pragma unroll
    for (int i = 0; i < 8; ++i) {
        afh[i] = *(const short8*)(vwhi + ((size_t)(i * 64 + lane)) * 8);
        afl[i] = *(const short8*)(vwlo + ((size_t)(i * 64 + lane)) * 8);
    }

    // geometry epilogue: per-thread pixel l0+tid, branch-free, coalesced
    {
        const int l = l0 + tid;
        const size_t fb = (size_t)b * 4 * Ll + l;
        float e[4], gm = -1e30f;
#pragma unroll
        for (int q = 0; q < 4; ++q) { e[q] = acc[q] + gate_b[q]; gm = fmaxf(gm, e[q]); }
        float gs = 0.f;
#pragma unroll
        for (int q = 0; q < 4; ++q) { e[q] = __expf(e[q] - gm); gs += e[q]; }
        const float gi = __fdividef(1.f, gs);
#pragma unroll
        for (int q = 0; q < 4; ++q) {
            mu[fb + (size_t)q * Ll] = e[q] * gi;
            float sv, cv;
            __sincosf(2.f * (acc[4 + q] + geom_b[q]), &sv, &cv);
            cs2[fb + (size_t)q * Ll] = cv;
            sn2[fb + (size_t)q * Ll] = sv;
            bse[fb + (size_t)q * Ll] = softplusf(acc[8 + q]  + geom_b[4 + q]) + 1e-4f;
            hyp[fb + (size_t)q * Ll] = softplusf(acc[12 + q] + geom_b[8 + q]);
        }
    }

    __syncthreads();

    // value channels via MFMA (hi/lo split, 3 of 4 cross terms)
    const int px = lane & 15;
    const int g  = lane >> 4;

#pragma unroll 1
    for (int pi = 0; pi < 4; ++pi) {
        const int pt  = w * 4 + pi;
        const int row = pt * 16 + px;
        const short8 bh0 = *(const short8*)&xhi[row][g * 8];
        const short8 bh1 = *(const short8*)&xhi[row][32 + g * 8];
        const short8 bl0 = *(const short8*)&xlo[row][g * 8];
        const short8 bl1 = *(const short8*)&xlo[row][32 + g * 8];

        f32x4 d0, d1, d2, d3;
#define PROJ_TILE(dst, t)                                              \
        {                                                              \
            f32x4 a_ = {0.f, 0.f, 0.f, 0.f};                           \
            a_ = __builtin_amdgcn_mfma_f32_16x16x32_bf16(afh[2*(t)],   bh0, a_, 0, 0, 0); \
            a_ = __builtin_amdgcn_mfma_f32_16x16x32_bf16(afh[2*(t)+1], bh1, a_, 0, 0, 0); \
            a_ = __builtin_amdgcn_mfma_f32_16x16x32_bf16(afh[2*(t)],   bl0, a_, 0, 0, 0); \
            a_ = __builtin_amdgcn_mfma_f32_16x16x32_bf16(afh[2*(t)+1], bl1, a_, 0, 0, 0); \
            a_ = __builtin_amdgcn_mfma_f32_16x16x32_bf16(afl[2*(t)],   bh0, a_, 0, 0, 0); \
            a_ = __builtin_amdgcn_mfma_f32_16x16x32_bf16(afl[2*(t)+1], bh1, a_, 0, 0, 0); \
            dst = a_;                                                  \
        }
        PROJ_TILE(d0, 0) PROJ_TILE(d1, 1) PROJ_TILE(d2, 2) PROJ_TILE(d3, 3)
#undef PROJ_TILE

        // lane holds v channels c = 16t + 4g + q for pixel l0 + pt*16 + px
        const int l = l0 + pt * 16 + px;
        float* vrow = v + ((size_t)b * Ll + l) * 64 + g * 4;
        *(f32x4*)(vrow)      = d0;
        *(f32x4*)(vrow + 16) = d1;
        *(f32x4*)(vrow + 32) = d2;
        *(f32x4*)(vrow + 48) = d3;
    }
}

// ---------------- k23: fused compat + aggregation + MFMA pointwise ----------------
// TP=64 pixels (one half-row), 256 threads = 4 waves.
// Stage A (lane=pixel): thread (px, r=wave) computes the 9 normalized compat
// weights for its (pixel, rule) into LDS wqlds[px][r*12+s].
// Stage B (lane=channel): wave w owns px w*16..+15; 54 hoisted v-lines
// (clamped; OOB weight = 0); wq via uniform LDS b128 broadcasts; packed uint2
// agg write (m' = c*4+r). Stage C: wave w -> o-tile w*16; A-frags pre-barrier;
// reused across 4 p-tiles; bias as C-init.
__global__ __launch_bounds__(256) void k23_fused(
    const float* __restrict__ mu,
    const float* __restrict__ cs2, const float* __restrict__ sn2,
    const float* __restrict__ bse, const float* __restrict__ hyp,
    const float* __restrict__ v,             // [B][L][64]
    const unsigned short* __restrict__ pwb16,// [64][256] bf16, m'-order
    const float* __restrict__ pw_b,          // [64]
    float* __restrict__ out)                 // [B][64][L]
{
    __shared__ float wqlds[TP * 52];         // [px][r*12+s], rows 208B
    __shared__ unsigned short agg[TP][264];  // bf16, rows 528B

    const int tid = threadIdx.x;
    const int pix0 = blockIdx.x * TP;
    const int b = pix0 >> 14;
    const int l0 = pix0 & (Ll - 1);

    // ---- stage A: lane = pixel ----
    {
        const int px = tid & 63;
        const int r  = tid >> 6;
        const int l  = l0 + px;
        const int hr = l >> 7;
        const int wc = l & (Ww - 1);
        const size_t fb = ((size_t)b * 4 + r) * Ll;

        const float cc = cs2[fb + l], sc = sn2[fb + l];
        const float bc = bse[fb + l], yc = hyp[fb + l];
        const float mc = mu[fb + l];

        float cmp[9];
        float sum = 0.f;
#pragma unroll
        for (int s = 0; s < 9; ++s) {
            const int dy = s / 3 - 1, dx = s % 3 - 1;
            float cv;
            if (dx == 0 && dy == 0) {
                cv = mc;
            } else {
                const int hh = hr + dy, ww = wc + dx;
                const int hcl = min(max(hh, 0), Hh - 1);
                const int wcl = min(max(ww, 0), Ww - 1);
                const bool inb = ((unsigned)hh < (unsigned)Hh) &
                                 ((unsigned)ww < (unsigned)Ww);
                const size_t ni = fb + hcl * Ww + wcl;
                const float cn = cs2[ni], sn = sn2[ni];
                const float bn = bse[ni], yn = hyp[ni];
                const float mun = inb ? mu[ni] : 0.f;
                const float c2 = cc + cn, s2 = sc + sn;
                const float h = sqrtf(fmaxf(c2 * c2 + s2 * s2, 1e-24f));
                const float rh = __fdividef(0.5f, h);
                float pu2, ps2;
                if (dx != 0 && dy != 0) {              // diagonal
                    const float t = 2.f * (float)(dx * dy) * (s2 * rh);
                    pu2 = 1.f + t; ps2 = 1.f - t;
                } else if (dx != 0) {                  // horizontal
                    pu2 = 0.5f + c2 * rh; ps2 = 0.5f - c2 * rh;
                } else {                               // vertical
                    pu2 = 0.5f - c2 * rh; ps2 = 0.5f + c2 * rh;
                }
                const float bp = 0.5f * (bc + bn);
                const float hp = 0.5f * (yc + yn);
                const float E = __expf(hp);
                const float iu = __fdividef(1.f, bp * E);   // 1/sigma_u
                const float is = E * E * iu;                // 1/sigma_s
                const float q = pu2 * (iu * iu) + ps2 * (is * is);
                cv = __expf(-q) * mun;
            }
            cmp[s] = cv;
            sum += cv;
        }
        const float inv = __fdividef(1.f, sum + 1e-6f);
        float* wrow = &wqlds[px * 52 + r * 12];
#pragma unroll
        for (int s = 0; s < 9; ++s) wrow[s] = cmp[s] * inv;
    }
    __syncthreads();

    // ---- stage B: lane = channel ----
    const int w = tid >> 6, c = tid & 63;
    {
        const int hr0  = l0 >> 7;
        const int rows[3] = { max(hr0 - 1, 0) * Ww, hr0 * Ww, min(hr0 + 1, Hh - 1) * Ww };
        const int colbase = (l0 & (Ww - 1)) + w * 16;
        const float* vb = v + ((size_t)b * Ll) * 64 + c;

        float vv[3][18];
#pragma unroll
        for (int ry = 0; ry < 3; ++ry)
#pragma unroll
            for (int cx = 0; cx < 18; ++cx) {
                const int col = min(max(colbase + cx - 1, 0), Ww - 1);
                vv[ry][cx] = vb[(size_t)(rows[ry] + col) * 64];
            }

#pragma unroll
        for (int p = 0; p < 16; ++p) {
            const float* wrow = &wqlds[(w * 16 + p) * 52];
            unsigned pk[2];
#pragma unroll
            for (int r = 0; r < 4; ++r) {
                const float4 w0 = *(const float4*)(wrow + r * 12);      // s0..3
                const float4 w1 = *(const float4*)(wrow + r * 12 + 4);  // s4..7
                const float  w8 = wrow[r * 12 + 8];
                float a;
                a = w0.x * vv[0][p];
                a = fmaf(w0.y, vv[0][p + 1], a);
                a = fmaf(w0.z, vv[0][p + 2], a);
                a = fmaf(w0.w, vv[1][p],     a);
                a = fmaf(w1.x, vv[1][p + 1], a);
                a = fmaf(w1.y, vv[1][p + 2], a);
                a = fmaf(w1.z, vv[2][p],     a);
                a = fmaf(w1.w, vv[2][p + 1], a);
                a = fmaf(w8,   vv[2][p + 2], a);
                if (r & 1) pk[r >> 1] |= (unsigned)f32_to_bf16(a) << 16;
                else       pk[r >> 1]  = (unsigned)f32_to_bf16(a);
            }
            uint2 u; u.x = pk[0]; u.y = pk[1];
            *((uint2*)(&agg[w * 16 + p][0]) + c) = u;   // m' = c*4+r
        }
    }

    // A fragments: issue before the barrier (in flight across it)
    const int ar    = tid & 15;
    const int chunk = (tid >> 4) & 3;
    const int o0    = w * 16;
    const unsigned short* aPtr = pwb16 + (o0 + ar) * 256 + chunk * 8;
    short8 af[8];
#pragma unroll
    for (int kt = 0; kt < 8; ++kt) af[kt] = *(const short8*)(aPtr + kt * 32);

    __syncthreads();

    // ---- stage C: MFMA pointwise, 4 p-tiles, A reused ----
    f32x4 d0, d1, d2, d3;
#pragma unroll
    for (int q = 0; q < 4; ++q) {
        const float bv = pw_b[o0 + chunk * 4 + q];
        d0[q] = bv; d1[q] = bv; d2[q] = bv; d3[q] = bv;
    }
    const unsigned short* b0 = &agg[ 0 + ar][chunk * 8];
    const unsigned short* b1 = &agg[16 + ar][chunk * 8];
    const unsigned short* b2 = &agg[32 + ar][chunk * 8];
    const unsigned short* b3 = &agg[48 + ar][chunk * 8];
#pragma unroll
    for (int kt = 0; kt < 8; ++kt) {
        d0 = __builtin_amdgcn_mfma_f32_16x16x32_bf16(af[kt], *(const short8*)(b0 + kt * 32), d0, 0, 0, 0);
        d1 = __builtin_amdgcn_mfma_f32_16x16x32_bf16(af[kt], *(const short8*)(b1 + kt * 32), d1, 0, 0, 0);
        d2 = __builtin_amdgcn_mfma_f32_16x16x32_bf16(af[kt], *(const short8*)(b2 + kt * 32), d2, 0, 0, 0);
        d3 = __builtin_amdgcn_mfma_f32_16x16x32_bf16(af[kt], *(const short8*)(b3 + kt * 32), d3, 0, 0, 0);
    }

#pragma unroll
    for (int q = 0; q < 4; ++q) {
        const int o = o0 + chunk * 4 + q;
        float* ob = out + ((size_t)b * Co + o) * Ll + l0 + ar;
        ob[0]  = d0[q];
        ob[16] = d1[q];
        ob[32] = d2[q];
        ob[48] = d3[q];
    }
}

// ---------------- launch ----------------
extern "C" void kernel_launch(void* const* d_in, const int* in_sizes, int n_in,
                              void* d_out, int out_size, void* d_ws, size_t ws_size,
                              hipStream_t stream)
{
    const float* x       = (const float*)d_in[0];
    const float* gate_w  = (const float*)d_in[1];
    const float* gate_b  = (const float*)d_in[2];
    const float* value_w = (const float*)d_in[3];
    const float* geom_w  = (const float*)d_in[4];
    const float* geom_b  = (const float*)d_in[5];
    const float* pw_w    = (const float*)d_in[6];
    const float* pw_b    = (const float*)d_in[7];
    float* out = (float*)d_out;

    float* ws  = (float*)d_ws;
    float* v    = ws;                                  // B*L*64   = 8388608
    float* mu   = v    + (size_t)Bx * Ll * 64;         // B*4*L    = 524288
    float* cs2  = mu   + (size_t)Bx * 4 * Ll;
    float* sn2  = cs2  + (size_t)Bx * 4 * Ll;
    float* bse  = sn2  + (size_t)Bx * 4 * Ll;
    float* hyp  = bse  + (size_t)Bx * 4 * Ll;
    float* wt16 = hyp  + (size_t)Bx * 4 * Ll;                 // 1024 f
    unsigned short* vwhi  = (unsigned short*)(wt16 + 1024);   // 4096 us
    unsigned short* vwlo  = vwhi + 4096;                      // 4096 us
    unsigned short* pwb16 = vwlo + 4096;                      // 16384 us
    // total ws: ~44 MB

    k0_pack_weights<<<1, 256, 0, stream>>>(gate_w, geom_w, value_w, pw_w,
                                           wt16, vwhi, vwlo, pwb16);
    k1_project<<<NPIX / 256, 256, 0, stream>>>(x, vwhi, vwlo, wt16, gate_b, geom_b,
                                               v, mu, cs2, sn2, bse, hyp);
    k23_fused<<<NPIX / TP, 256, 0, stream>>>(mu, cs2, sn2, bse, hyp,
                                             v, pwb16, pw_b, out);
}

// Round 8
// 124.434 us; speedup vs baseline: 1.3196x; 1.3196x over previous
//
#include <hip/hip_runtime.h>

namespace {
constexpr int Bx = 8, Cc = 64, Hh = 128, Ww = 128, Co = 64;
constexpr int Ll = Hh * Ww;        // 16384 = 2^14
constexpr int NPIX = Bx * Ll;      // 131072
constexpr int TP = 64;             // pixels per block in k23
}

using short8 = __attribute__((ext_vector_type(8))) short;
using f32x4  = __attribute__((ext_vector_type(4))) float;

__device__ __forceinline__ unsigned short f32_to_bf16(float f) {
    union { float f; unsigned u; } un; un.f = f;
    unsigned r = un.u + 0x7FFFu + ((un.u >> 16) & 1u);   // round-to-nearest-even
    return (unsigned short)(r >> 16);
}

// ---------------- k0: pack weights ----------------
// wt16 [c][16] fp32: gate(4) + geom(12) — k1's scalar path (fp32 required:
// the theta half-angle math is chaotically sensitive; bf16 there fails).
// vwb16: value_w as MFMA A-frags (single bf16), [t=4][ks=2][lane=64][jj=8]:
//   A row = t*16+(lane&15) = value out channel, k = ks*32+(lane>>4)*8+jj = c.
// pwb16 k-order m' = c*4+r (matches k23's packed agg writes).
__global__ __launch_bounds__(256) void k0_pack_weights(
    const float* __restrict__ gate_w,   // [4][64]
    const float* __restrict__ geom_w,   // [12][64]
    const float* __restrict__ value_w,  // [64][64]
    const float* __restrict__ pw_w,     // [64][256], m = r*64+c
    float* __restrict__ wt16,           // [64][16]
    unsigned short* __restrict__ vwb16, // [4096]
    unsigned short* __restrict__ pwb16) // [64][256] bf16, m' = c*4+r
{
    for (int idx = threadIdx.x; idx < Cc * 16; idx += 256) {
        const int c = idx >> 4, j = idx & 15;
        wt16[idx] = (j < 4) ? gate_w[j * Cc + c] : geom_w[(j - 4) * Cc + c];
    }
    for (int flat = threadIdx.x; flat < 4096; flat += 256) {
        const int t    = flat >> 10;
        const int ks   = (flat >> 9) & 1;
        const int lane = (flat >> 3) & 63;
        const int jj   = flat & 7;
        const int j = t * 16 + (lane & 15);
        const int c = ks * 32 + ((lane >> 4) & 3) * 8 + jj;
        vwb16[flat] = f32_to_bf16(value_w[j * Cc + c]);
    }
    for (int idx = threadIdx.x; idx < Co * 256; idx += 256) {
        const int o = idx >> 8, m = idx & 255;
        const int r = m >> 6, c = m & 63;
        pwb16[o * 256 + c * 4 + r] = f32_to_bf16(pw_w[idx]);
    }
}

__device__ __forceinline__ float softplusf(float v) {
    return v > 20.f ? v : log1pf(__expf(v));
}

// ---------------- k1: hybrid projections (36 KB LDS, 4 blocks/CU) ----------------
// Thread tid stages pixel l0+tid's 64 x values into LDS as SINGLE bf16 and
// accumulates the 16 gate/geom outputs in fp32 scalar FMA. Value channels via
// plain bf16 MFMA (v-input rounding adds in quadrature with k23's agg-bf16
// rounding: measured-equal absmax at fp32-v, so precision headroom is ample).
// Wave w owns px-tiles w*4..+3, 4 j-tiles x 2 MFMAs, v stored fp32 pixel-major.
__global__ __launch_bounds__(256, 4) void k1_project(
    const float* __restrict__ x,       // [B][64][L]
    const unsigned short* __restrict__ vwb16,
    const float* __restrict__ wt16,    // [64][16]
    const float* __restrict__ gate_b,  // [4]
    const float* __restrict__ geom_b,  // [12]
    float* __restrict__ v,             // [B][L][64]  (pixel-major)
    float* __restrict__ mu,            // [B][4][L]
    float* __restrict__ cs2, float* __restrict__ sn2,
    float* __restrict__ bse, float* __restrict__ hyp)  // each [B][4][L]
{
    __shared__ unsigned short xb16[256][72];  // 36,864 B -> 4 blocks/CU

    const int tid  = threadIdx.x;
    const int lane = tid & 63;
    const int w    = tid >> 6;
    const int pix0 = blockIdx.x * 256;
    const int b    = pix0 >> 14;
    const int l0   = pix0 & (Ll - 1);

    // stage X -> LDS bf16 + fp32 scalar gate/geom accumulation
    float acc[16];
#pragma unroll
    for (int j = 0; j < 16; ++j) acc[j] = 0.f;

    const float* xb = x + (size_t)b * Cc * Ll + (l0 + tid);
#pragma unroll
    for (int c0 = 0; c0 < 64; c0 += 8) {
        float xv[8];
#pragma unroll
        for (int j = 0; j < 8; ++j) xv[j] = xb[(size_t)(c0 + j) * Ll];
        uint4 ph;
        unsigned* hp = (unsigned*)&ph;
#pragma unroll
        for (int j = 0; j < 4; ++j)
            hp[j] = (unsigned)f32_to_bf16(xv[2 * j]) |
                    ((unsigned)f32_to_bf16(xv[2 * j + 1]) << 16);
        *(uint4*)&xb16[tid][c0] = ph;
#pragma unroll
        for (int j = 0; j < 8; ++j) {
            const float* wr = wt16 + (c0 + j) * 16;   // uniform -> s_load
#pragma unroll
            for (int jj = 0; jj < 16; ++jj) acc[jj] = fmaf(wr[jj], xv[j], acc[jj]);
        }
    }

    // A fragments (value weights) — issue early, consumed after barrier
    short8 af[8];
#pragma unroll
    for (int i = 0; i < 8; ++i)
        af[i] = *(const short8*)(vwb16 + ((size_t)(i * 64 + lane)) * 8);

    // geometry epilogue: per-thread pixel l0+tid, branch-free, coalesced
    {
        const int l = l0 + tid;
        const size_t fb = (size_t)b * 4 * Ll + l;
        float e[4], gm = -1e30f;
#pragma unroll
        for (int q = 0; q < 4; ++q) { e[q] = acc[q] + gate_b[q]; gm = fmaxf(gm, e[q]); }
        float gs = 0.f;
#pragma unroll
        for (int q = 0; q < 4; ++q) { e[q] = __expf(e[q] - gm); gs += e[q]; }
        const float gi = __fdividef(1.f, gs);
#pragma unroll
        for (int q = 0; q < 4; ++q) {
            mu[fb + (size_t)q * Ll] = e[q] * gi;
            float sv, cv;
            __sincosf(2.f * (acc[4 + q] + geom_b[q]), &sv, &cv);
            cs2[fb + (size_t)q * Ll] = cv;
            sn2[fb + (size_t)q * Ll] = sv;
            bse[fb + (size_t)q * Ll] = softplusf(acc[8 + q]  + geom_b[4 + q]) + 1e-4f;
            hyp[fb + (size_t)q * Ll] = softplusf(acc[12 + q] + geom_b[8 + q]);
        }
    }

    __syncthreads();

    // value channels via single-bf16 MFMA
    const int px = lane & 15;
    const int g  = lane >> 4;

#pragma unroll 1
    for (int pi = 0; pi < 4; ++pi) {
        const int pt  = w * 4 + pi;
        const int row = pt * 16 + px;
        const short8 bh0 = *(const short8*)&xb16[row][g * 8];
        const short8 bh1 = *(const short8*)&xb16[row][32 + g * 8];

        f32x4 d0, d1, d2, d3;
#define PROJ_TILE(dst, t)                                              \
        {                                                              \
            f32x4 a_ = {0.f, 0.f, 0.f, 0.f};                           \
            a_ = __builtin_amdgcn_mfma_f32_16x16x32_bf16(af[2*(t)],   bh0, a_, 0, 0, 0); \
            a_ = __builtin_amdgcn_mfma_f32_16x16x32_bf16(af[2*(t)+1], bh1, a_, 0, 0, 0); \
            dst = a_;                                                  \
        }
        PROJ_TILE(d0, 0) PROJ_TILE(d1, 1) PROJ_TILE(d2, 2) PROJ_TILE(d3, 3)
#undef PROJ_TILE

        // lane holds v channels c = 16t + 4g + q for pixel l0 + pt*16 + px
        const int l = l0 + pt * 16 + px;
        float* vrow = v + ((size_t)b * Ll + l) * 64 + g * 4;
        *(f32x4*)(vrow)      = d0;
        *(f32x4*)(vrow + 16) = d1;
        *(f32x4*)(vrow + 32) = d2;
        *(f32x4*)(vrow + 48) = d3;
    }
}

// ---------------- k23: fused compat + aggregation + MFMA pointwise ----------------
// TP=64 pixels (one half-row), 256 threads = 4 waves. (unchanged from R5)
__global__ __launch_bounds__(256) void k23_fused(
    const float* __restrict__ mu,
    const float* __restrict__ cs2, const float* __restrict__ sn2,
    const float* __restrict__ bse, const float* __restrict__ hyp,
    const float* __restrict__ v,             // [B][L][64]
    const unsigned short* __restrict__ pwb16,// [64][256] bf16, m'-order
    const float* __restrict__ pw_b,          // [64]
    float* __restrict__ out)                 // [B][64][L]
{
    __shared__ float wqlds[TP * 52];         // [px][r*12+s], rows 208B
    __shared__ unsigned short agg[TP][264];  // bf16, rows 528B

    const int tid = threadIdx.x;
    const int pix0 = blockIdx.x * TP;
    const int b = pix0 >> 14;
    const int l0 = pix0 & (Ll - 1);

    // ---- stage A: lane = pixel ----
    {
        const int px = tid & 63;
        const int r  = tid >> 6;
        const int l  = l0 + px;
        const int hr = l >> 7;
        const int wc = l & (Ww - 1);
        const size_t fb = ((size_t)b * 4 + r) * Ll;

        const float cc = cs2[fb + l], sc = sn2[fb + l];
        const float bc = bse[fb + l], yc = hyp[fb + l];
        const float mc = mu[fb + l];

        float cmp[9];
        float sum = 0.f;
#pragma unroll
        for (int s = 0; s < 9; ++s) {
            const int dy = s / 3 - 1, dx = s % 3 - 1;
            float cv;
            if (dx == 0 && dy == 0) {
                cv = mc;
            } else {
                const int hh = hr + dy, ww = wc + dx;
                const int hcl = min(max(hh, 0), Hh - 1);
                const int wcl = min(max(ww, 0), Ww - 1);
                const bool inb = ((unsigned)hh < (unsigned)Hh) &
                                 ((unsigned)ww < (unsigned)Ww);
                const size_t ni = fb + hcl * Ww + wcl;
                const float cn = cs2[ni], sn = sn2[ni];
                const float bn = bse[ni], yn = hyp[ni];
                const float mun = inb ? mu[ni] : 0.f;
                const float c2 = cc + cn, s2 = sc + sn;
                const float h = sqrtf(fmaxf(c2 * c2 + s2 * s2, 1e-24f));
                const float rh = __fdividef(0.5f, h);
                float pu2, ps2;
                if (dx != 0 && dy != 0) {              // diagonal
                    const float t = 2.f * (float)(dx * dy) * (s2 * rh);
                    pu2 = 1.f + t; ps2 = 1.f - t;
                } else if (dx != 0) {                  // horizontal
                    pu2 = 0.5f + c2 * rh; ps2 = 0.5f - c2 * rh;
                } else {                               // vertical
                    pu2 = 0.5f - c2 * rh; ps2 = 0.5f + c2 * rh;
                }
                const float bp = 0.5f * (bc + bn);
                const float hp = 0.5f * (yc + yn);
                const float E = __expf(hp);
                const float iu = __fdividef(1.f, bp * E);   // 1/sigma_u
                const float is = E * E * iu;                // 1/sigma_s
                const float q = pu2 * (iu * iu) + ps2 * (is * is);
                cv = __expf(-q) * mun;
            }
            cmp[s] = cv;
            sum += cv;
        }
        const float inv = __fdividef(1.f, sum + 1e-6f);
        float* wrow = &wqlds[px * 52 + r * 12];
#pragma unroll
        for (int s = 0; s < 9; ++s) wrow[s] = cmp[s] * inv;
    }
    __syncthreads();

    // ---- stage B: lane = channel ----
    const int w = tid >> 6, c = tid & 63;
    {
        const int hr0  = l0 >> 7;
        const int rows[3] = { max(hr0 - 1, 0) * Ww, hr0 * Ww, min(hr0 + 1, Hh - 1) * Ww };
        const int colbase = (l0 & (Ww - 1)) + w * 16;
        const float* vb = v + ((size_t)b * Ll) * 64 + c;

        float vv[3][18];
#pragma unroll
        for (int ry = 0; ry < 3; ++ry)
#pragma unroll
            for (int cx = 0; cx < 18; ++cx) {
                const int col = min(max(colbase + cx - 1, 0), Ww - 1);
                vv[ry][cx] = vb[(size_t)(rows[ry] + col) * 64];
            }

#pragma unroll
        for (int p = 0; p < 16; ++p) {
            const float* wrow = &wqlds[(w * 16 + p) * 52];
            unsigned pk[2];
#pragma unroll
            for (int r = 0; r < 4; ++r) {
                const float4 w0 = *(const float4*)(wrow + r * 12);      // s0..3
                const float4 w1 = *(const float4*)(wrow + r * 12 + 4);  // s4..7
                const float  w8 = wrow[r * 12 + 8];
                float a;
                a = w0.x * vv[0][p];
                a = fmaf(w0.y, vv[0][p + 1], a);
                a = fmaf(w0.z, vv[0][p + 2], a);
                a = fmaf(w0.w, vv[1][p],     a);
                a = fmaf(w1.x, vv[1][p + 1], a);
                a = fmaf(w1.y, vv[1][p + 2], a);
                a = fmaf(w1.z, vv[2][p],     a);
                a = fmaf(w1.w, vv[2][p + 1], a);
                a = fmaf(w8,   vv[2][p + 2], a);
                if (r & 1) pk[r >> 1] |= (unsigned)f32_to_bf16(a) << 16;
                else       pk[r >> 1]  = (unsigned)f32_to_bf16(a);
            }
            uint2 u; u.x = pk[0]; u.y = pk[1];
            *((uint2*)(&agg[w * 16 + p][0]) + c) = u;   // m' = c*4+r
        }
    }

    // A fragments: issue before the barrier (in flight across it)
    const int ar    = tid & 15;
    const int chunk = (tid >> 4) & 3;
    const int o0    = w * 16;
    const unsigned short* aPtr = pwb16 + (o0 + ar) * 256 + chunk * 8;
    short8 af[8];
#pragma unroll
    for (int kt = 0; kt < 8; ++kt) af[kt] = *(const short8*)(aPtr + kt * 32);

    __syncthreads();

    // ---- stage C: MFMA pointwise, 4 p-tiles, A reused ----
    f32x4 d0, d1, d2, d3;
#pragma unroll
    for (int q = 0; q < 4; ++q) {
        const float bv = pw_b[o0 + chunk * 4 + q];
        d0[q] = bv; d1[q] = bv; d2[q] = bv; d3[q] = bv;
    }
    const unsigned short* b0 = &agg[ 0 + ar][chunk * 8];
    const unsigned short* b1 = &agg[16 + ar][chunk * 8];
    const unsigned short* b2 = &agg[32 + ar][chunk * 8];
    const unsigned short* b3 = &agg[48 + ar][chunk * 8];
#pragma unroll
    for (int kt = 0; kt < 8; ++kt) {
        d0 = __builtin_amdgcn_mfma_f32_16x16x32_bf16(af[kt], *(const short8*)(b0 + kt * 32), d0, 0, 0, 0);
        d1 = __builtin_amdgcn_mfma_f32_16x16x32_bf16(af[kt], *(const short8*)(b1 + kt * 32), d1, 0, 0, 0);
        d2 = __builtin_amdgcn_mfma_f32_16x16x32_bf16(af[kt], *(const short8*)(b2 + kt * 32), d2, 0, 0, 0);
        d3 = __builtin_amdgcn_mfma_f32_16x16x32_bf16(af[kt], *(const short8*)(b3 + kt * 32), d3, 0, 0, 0);
    }

#pragma unroll
    for (int q = 0; q < 4; ++q) {
        const int o = o0 + chunk * 4 + q;
        float* ob = out + ((size_t)b * Co + o) * Ll + l0 + ar;
        ob[0]  = d0[q];
        ob[16] = d1[q];
        ob[32] = d2[q];
        ob[48] = d3[q];
    }
}

// ---------------- launch ----------------
extern "C" void kernel_launch(void* const* d_in, const int* in_sizes, int n_in,
                              void* d_out, int out_size, void* d_ws, size_t ws_size,
                              hipStream_t stream)
{
    const float* x       = (const float*)d_in[0];
    const float* gate_w  = (const float*)d_in[1];
    const float* gate_b  = (const float*)d_in[2];
    const float* value_w = (const float*)d_in[3];
    const float* geom_w  = (const float*)d_in[4];
    const float* geom_b  = (const float*)d_in[5];
    const float* pw_w    = (const float*)d_in[6];
    const float* pw_b    = (const float*)d_in[7];
    float* out = (float*)d_out;

    float* ws  = (float*)d_ws;
    float* v    = ws;                                  // B*L*64   = 8388608
    float* mu   = v    + (size_t)Bx * Ll * 64;         // B*4*L    = 524288
    float* cs2  = mu   + (size_t)Bx * 4 * Ll;
    float* sn2  = cs2  + (size_t)Bx * 4 * Ll;
    float* bse  = sn2  + (size_t)Bx * 4 * Ll;
    float* hyp  = bse  + (size_t)Bx * 4 * Ll;
    float* wt16 = hyp  + (size_t)Bx * 4 * Ll;                 // 1024 f
    unsigned short* vwb16 = (unsigned short*)(wt16 + 1024);   // 4096 us
    unsigned short* pwb16 = vwb16 + 4096;                     // 16384 us
    // total ws: ~44 MB

    k0_pack_weights<<<1, 256, 0, stream>>>(gate_w, geom_w, value_w, pw_w,
                                           wt16, vwb16, pwb16);
    k1_project<<<NPIX / 256, 256, 0, stream>>>(x, vwb16, wt16, gate_b, geom_b,
                                               v, mu, cs2, sn2, bse, hyp);
    k23_fused<<<NPIX / TP, 256, 0, stream>>>(mu, cs2, sn2, bse, hyp,
                                             v, pwb16, pw_b, out);
}

// Round 11
// 86.570 us; speedup vs baseline: 1.8968x; 1.4374x over previous
//
#include <hip/hip_runtime.h>

namespace {
constexpr int Bx = 8, Cc = 64, Hh = 128, Ww = 128, Co = 64;
constexpr int Ll = Hh * Ww;        // 16384 = 2^14
constexpr int NPIX = Bx * Ll;      // 131072
constexpr int TP = 64;             // pixels per block in k23
}

using short8 = __attribute__((ext_vector_type(8))) short;
using f32x4  = __attribute__((ext_vector_type(4))) float;

__device__ __forceinline__ unsigned short f32_to_bf16(float f) {
    union { float f; unsigned u; } un; un.f = f;
    unsigned r = un.u + 0x7FFFu + ((un.u >> 16) & 1u);   // round-to-nearest-even
    return (unsigned short)(r >> 16);
}

// ---------------- k0: pack weights ----------------
// wt16 [c][16] fp32: gate(4) + geom(12) — k1's scalar path (fp32 required:
// the theta half-angle math is chaotically sensitive; bf16 there fails).
// vwb16: value_w as MFMA A-frags (single bf16), [t=4][ks=2][lane=64][jj=8]:
//   A row = t*16+(lane&15) = value out channel, k = ks*32+(lane>>4)*8+jj = c.
// pwb16 k-order m' = c*4+r (matches k23's packed agg writes).
__global__ __launch_bounds__(256) void k0_pack_weights(
    const float* __restrict__ gate_w,   // [4][64]
    const float* __restrict__ geom_w,   // [12][64]
    const float* __restrict__ value_w,  // [64][64]
    const float* __restrict__ pw_w,     // [64][256], m = r*64+c
    float* __restrict__ wt16,           // [64][16]
    unsigned short* __restrict__ vwb16, // [4096]
    unsigned short* __restrict__ pwb16) // [64][256] bf16, m' = c*4+r
{
    for (int idx = threadIdx.x; idx < Cc * 16; idx += 256) {
        const int c = idx >> 4, j = idx & 15;
        wt16[idx] = (j < 4) ? gate_w[j * Cc + c] : geom_w[(j - 4) * Cc + c];
    }
    for (int flat = threadIdx.x; flat < 4096; flat += 256) {
        const int t    = flat >> 10;
        const int ks   = (flat >> 9) & 1;
        const int lane = (flat >> 3) & 63;
        const int jj   = flat & 7;
        const int j = t * 16 + (lane & 15);
        const int c = ks * 32 + ((lane >> 4) & 3) * 8 + jj;
        vwb16[flat] = f32_to_bf16(value_w[j * Cc + c]);
    }
    for (int idx = threadIdx.x; idx < Co * 256; idx += 256) {
        const int o = idx >> 8, m = idx & 255;
        const int r = m >> 6, c = m & 63;
        pwb16[o * 256 + c * 4 + r] = f32_to_bf16(pw_w[idx]);
    }
}

__device__ __forceinline__ float softplusf(float v) {
    return v > 20.f ? v : log1pf(__expf(v));
}

// ---------------- k1: hybrid projections, 64 px/block (grid 2048) ----------------
// 1-px-per-thread caps at 8 waves/CU (grid 512) — latency-bound. Here 4
// threads share a pixel: thread (ch=tid>>6, px=tid&63) loads its 16 x
// channels (coalesced in px), stages bf16 to LDS, accumulates PARTIAL fp32
// gate/geom sums; partials reduced through LDS (stride-17: conflict-free).
// Epilogue distributed: wave g handles {softmax | sincos | base | hyper}.
// Value channels via bf16 MFMA: wave ch owns p-tile ch (16 px), 8 MFMAs.
__global__ __launch_bounds__(256) void k1_project(
    const float* __restrict__ x,       // [B][64][L]
    const unsigned short* __restrict__ vwb16,
    const float* __restrict__ wt16,    // [64][16]
    const float* __restrict__ gate_b,  // [4]
    const float* __restrict__ geom_b,  // [12]
    float* __restrict__ v,             // [B][L][64]  (pixel-major)
    float* __restrict__ mu,            // [B][4][L]
    float* __restrict__ cs2, float* __restrict__ sn2,
    float* __restrict__ bse, float* __restrict__ hyp)  // each [B][4][L]
{
    __shared__ unsigned short xb16[64][72];   // 9,216 B
    __shared__ float part[4][64][17];         // 17,408 B; total 26.6 KB

    const int tid  = threadIdx.x;
    const int px   = tid & 63;
    const int ch   = tid >> 6;               // channel-quarter / wave id
    const int lane = tid & 63;
    const int pix0 = blockIdx.x * 64;
    const int b    = pix0 >> 14;
    const int l0   = pix0 & (Ll - 1);

    // stage my 16 channels + partial gate/geom accumulation
    float acc[16];
#pragma unroll
    for (int j = 0; j < 16; ++j) acc[j] = 0.f;

    const float* xb = x + (size_t)b * Cc * Ll + (l0 + px);
#pragma unroll
    for (int j0 = 0; j0 < 16; j0 += 8) {
        float xv[8];
#pragma unroll
        for (int j = 0; j < 8; ++j) xv[j] = xb[(size_t)(ch * 16 + j0 + j) * Ll];
        uint4 ph;
        unsigned* hp = (unsigned*)&ph;
#pragma unroll
        for (int j = 0; j < 4; ++j)
            hp[j] = (unsigned)f32_to_bf16(xv[2 * j]) |
                    ((unsigned)f32_to_bf16(xv[2 * j + 1]) << 16);
        *(uint4*)&xb16[px][ch * 16 + j0] = ph;
#pragma unroll
        for (int j = 0; j < 8; ++j) {
            const float* wr = wt16 + (ch * 16 + j0 + j) * 16;   // uniform
#pragma unroll
            for (int jj = 0; jj < 16; ++jj) acc[jj] = fmaf(wr[jj], xv[j], acc[jj]);
        }
    }
#pragma unroll
    for (int jj = 0; jj < 16; ++jj) part[ch][px][jj] = acc[jj];

    // A fragments (value weights) — issue early, consumed after barrier
    short8 af[8];
#pragma unroll
    for (int i = 0; i < 8; ++i)
        af[i] = *(const short8*)(vwb16 + ((size_t)(i * 64 + lane)) * 8);

    __syncthreads();

    // distributed epilogue: wave g handles output group g for all 64 px
    {
        const int g = ch;
        const int l = l0 + px;
        const size_t fb = (size_t)b * 4 * Ll + l;
        float o[4];
#pragma unroll
        for (int q = 0; q < 4; ++q)
            o[q] = part[0][px][4 * g + q] + part[1][px][4 * g + q]
                 + part[2][px][4 * g + q] + part[3][px][4 * g + q];
        if (g == 0) {
            float e[4], gm = -1e30f;
#pragma unroll
            for (int q = 0; q < 4; ++q) { e[q] = o[q] + gate_b[q]; gm = fmaxf(gm, e[q]); }
            float gs = 0.f;
#pragma unroll
            for (int q = 0; q < 4; ++q) { e[q] = __expf(e[q] - gm); gs += e[q]; }
            const float gi = __fdividef(1.f, gs);
#pragma unroll
            for (int q = 0; q < 4; ++q) mu[fb + (size_t)q * Ll] = e[q] * gi;
        } else if (g == 1) {
#pragma unroll
            for (int q = 0; q < 4; ++q) {
                float sv, cv;
                __sincosf(2.f * (o[q] + geom_b[q]), &sv, &cv);
                cs2[fb + (size_t)q * Ll] = cv;
                sn2[fb + (size_t)q * Ll] = sv;
            }
        } else if (g == 2) {
#pragma unroll
            for (int q = 0; q < 4; ++q)
                bse[fb + (size_t)q * Ll] = softplusf(o[q] + geom_b[4 + q]) + 1e-4f;
        } else {
#pragma unroll
            for (int q = 0; q < 4; ++q)
                hyp[fb + (size_t)q * Ll] = softplusf(o[q] + geom_b[8 + q]);
        }
    }

    // value channels via single-bf16 MFMA: wave ch owns p-tile ch
    const int px16 = lane & 15;
    const int g2   = lane >> 4;
    {
        const int row = ch * 16 + px16;
        const short8 bh0 = *(const short8*)&xb16[row][g2 * 8];
        const short8 bh1 = *(const short8*)&xb16[row][32 + g2 * 8];

        f32x4 d0, d1, d2, d3;
#define PROJ_TILE(dst, t)                                              \
        {                                                              \
            f32x4 a_ = {0.f, 0.f, 0.f, 0.f};                           \
            a_ = __builtin_amdgcn_mfma_f32_16x16x32_bf16(af[2*(t)],   bh0, a_, 0, 0, 0); \
            a_ = __builtin_amdgcn_mfma_f32_16x16x32_bf16(af[2*(t)+1], bh1, a_, 0, 0, 0); \
            dst = a_;                                                  \
        }
        PROJ_TILE(d0, 0) PROJ_TILE(d1, 1) PROJ_TILE(d2, 2) PROJ_TILE(d3, 3)
#undef PROJ_TILE

        const int l = l0 + ch * 16 + px16;
        float* vrow = v + ((size_t)b * Ll + l) * 64 + g2 * 4;
        *(f32x4*)(vrow)      = d0;
        *(f32x4*)(vrow + 16) = d1;
        *(f32x4*)(vrow + 32) = d2;
        *(f32x4*)(vrow + 48) = d3;
    }
}

// ---------------- k23: fused compat + aggregation + MFMA pointwise ----------------
// TP=64 pixels (one half-row), 256 threads = 4 waves. (unchanged from R5)
__global__ __launch_bounds__(256) void k23_fused(
    const float* __restrict__ mu,
    const float* __restrict__ cs2, const float* __restrict__ sn2,
    const float* __restrict__ bse, const float* __restrict__ hyp,
    const float* __restrict__ v,             // [B][L][64]
    const unsigned short* __restrict__ pwb16,// [64][256] bf16, m'-order
    const float* __restrict__ pw_b,          // [64]
    float* __restrict__ out)                 // [B][64][L]
{
    __shared__ float wqlds[TP * 52];         // [px][r*12+s], rows 208B
    __shared__ unsigned short agg[TP][264];  // bf16, rows 528B

    const int tid = threadIdx.x;
    const int pix0 = blockIdx.x * TP;
    const int b = pix0 >> 14;
    const int l0 = pix0 & (Ll - 1);

    // ---- stage A: lane = pixel ----
    {
        const int px = tid & 63;
        const int r  = tid >> 6;
        const int l  = l0 + px;
        const int hr = l >> 7;
        const int wc = l & (Ww - 1);
        const size_t fb = ((size_t)b * 4 + r) * Ll;

        const float cc = cs2[fb + l], sc = sn2[fb + l];
        const float bc = bse[fb + l], yc = hyp[fb + l];
        const float mc = mu[fb + l];

        float cmp[9];
        float sum = 0.f;
#pragma unroll
        for (int s = 0; s < 9; ++s) {
            const int dy = s / 3 - 1, dx = s % 3 - 1;
            float cv;
            if (dx == 0 && dy == 0) {
                cv = mc;
            } else {
                const int hh = hr + dy, ww = wc + dx;
                const int hcl = min(max(hh, 0), Hh - 1);
                const int wcl = min(max(ww, 0), Ww - 1);
                const bool inb = ((unsigned)hh < (unsigned)Hh) &
                                 ((unsigned)ww < (unsigned)Ww);
                const size_t ni = fb + hcl * Ww + wcl;
                const float cn = cs2[ni], sn = sn2[ni];
                const float bn = bse[ni], yn = hyp[ni];
                const float mun = inb ? mu[ni] : 0.f;
                const float c2 = cc + cn, s2 = sc + sn;
                const float h = sqrtf(fmaxf(c2 * c2 + s2 * s2, 1e-24f));
                const float rh = __fdividef(0.5f, h);
                float pu2, ps2;
                if (dx != 0 && dy != 0) {              // diagonal
                    const float t = 2.f * (float)(dx * dy) * (s2 * rh);
                    pu2 = 1.f + t; ps2 = 1.f - t;
                } else if (dx != 0) {                  // horizontal
                    pu2 = 0.5f + c2 * rh; ps2 = 0.5f - c2 * rh;
                } else {                               // vertical
                    pu2 = 0.5f - c2 * rh; ps2 = 0.5f + c2 * rh;
                }
                const float bp = 0.5f * (bc + bn);
                const float hp = 0.5f * (yc + yn);
                const float E = __expf(hp);
                const float iu = __fdividef(1.f, bp * E);   // 1/sigma_u
                const float is = E * E * iu;                // 1/sigma_s
                const float q = pu2 * (iu * iu) + ps2 * (is * is);
                cv = __expf(-q) * mun;
            }
            cmp[s] = cv;
            sum += cv;
        }
        const float inv = __fdividef(1.f, sum + 1e-6f);
        float* wrow = &wqlds[px * 52 + r * 12];
#pragma unroll
        for (int s = 0; s < 9; ++s) wrow[s] = cmp[s] * inv;
    }
    __syncthreads();

    // ---- stage B: lane = channel ----
    const int w = tid >> 6, c = tid & 63;
    {
        const int hr0  = l0 >> 7;
        const int rows[3] = { max(hr0 - 1, 0) * Ww, hr0 * Ww, min(hr0 + 1, Hh - 1) * Ww };
        const int colbase = (l0 & (Ww - 1)) + w * 16;
        const float* vb = v + ((size_t)b * Ll) * 64 + c;

        float vv[3][18];
#pragma unroll
        for (int ry = 0; ry < 3; ++ry)
#pragma unroll
            for (int cx = 0; cx < 18; ++cx) {
                const int col = min(max(colbase + cx - 1, 0), Ww - 1);
                vv[ry][cx] = vb[(size_t)(rows[ry] + col) * 64];
            }

#pragma unroll
        for (int p = 0; p < 16; ++p) {
            const float* wrow = &wqlds[(w * 16 + p) * 52];
            unsigned pk[2];
#pragma unroll
            for (int r = 0; r < 4; ++r) {
                const float4 w0 = *(const float4*)(wrow + r * 12);      // s0..3
                const float4 w1 = *(const float4*)(wrow + r * 12 + 4);  // s4..7
                const float  w8 = wrow[r * 12 + 8];
                float a;
                a = w0.x * vv[0][p];
                a = fmaf(w0.y, vv[0][p + 1], a);
                a = fmaf(w0.z, vv[0][p + 2], a);
                a = fmaf(w0.w, vv[1][p],     a);
                a = fmaf(w1.x, vv[1][p + 1], a);
                a = fmaf(w1.y, vv[1][p + 2], a);
                a = fmaf(w1.z, vv[2][p],     a);
                a = fmaf(w1.w, vv[2][p + 1], a);
                a = fmaf(w8,   vv[2][p + 2], a);
                if (r & 1) pk[r >> 1] |= (unsigned)f32_to_bf16(a) << 16;
                else       pk[r >> 1]  = (unsigned)f32_to_bf16(a);
            }
            uint2 u; u.x = pk[0]; u.y = pk[1];
            *((uint2*)(&agg[w * 16 + p][0]) + c) = u;   // m' = c*4+r
        }
    }

    // A fragments: issue before the barrier (in flight across it)
    const int ar    = tid & 15;
    const int chunk = (tid >> 4) & 3;
    const int o0    = w * 16;
    const unsigned short* aPtr = pwb16 + (o0 + ar) * 256 + chunk * 8;
    short8 af[8];
#pragma unroll
    for (int kt = 0; kt < 8; ++kt) af[kt] = *(const short8*)(aPtr + kt * 32);

    __syncthreads();

    // ---- stage C: MFMA pointwise, 4 p-tiles, A reused ----
    f32x4 d0, d1, d2, d3;
#pragma unroll
    for (int q = 0; q < 4; ++q) {
        const float bv = pw_b[o0 + chunk * 4 + q];
        d0[q] = bv; d1[q] = bv; d2[q] = bv; d3[q] = bv;
    }
    const unsigned short* b0 = &agg[ 0 + ar][chunk * 8];
    const unsigned short* b1 = &agg[16 + ar][chunk * 8];
    const unsigned short* b2 = &agg[32 + ar][chunk * 8];
    const unsigned short* b3 = &agg[48 + ar][chunk * 8];
#pragma unroll
    for (int kt = 0; kt < 8; ++kt) {
        d0 = __builtin_amdgcn_mfma_f32_16x16x32_bf16(af[kt], *(const short8*)(b0 + kt * 32), d0, 0, 0, 0);
        d1 = __builtin_amdgcn_mfma_f32_16x16x32_bf16(af[kt], *(const short8*)(b1 + kt * 32), d1, 0, 0, 0);
        d2 = __builtin_amdgcn_mfma_f32_16x16x32_bf16(af[kt], *(const short8*)(b2 + kt * 32), d2, 0, 0, 0);
        d3 = __builtin_amdgcn_mfma_f32_16x16x32_bf16(af[kt], *(const short8*)(b3 + kt * 32), d3, 0, 0, 0);
    }

#pragma unroll
    for (int q = 0; q < 4; ++q) {
        const int o = o0 + chunk * 4 + q;
        float* ob = out + ((size_t)b * Co + o) * Ll + l0 + ar;
        ob[0]  = d0[q];
        ob[16] = d1[q];
        ob[32] = d2[q];
        ob[48] = d3[q];
    }
}

// ---------------- launch ----------------
extern "C" void kernel_launch(void* const* d_in, const int* in_sizes, int n_in,
                              void* d_out, int out_size, void* d_ws, size_t ws_size,
                              hipStream_t stream)
{
    const float* x       = (const float*)d_in[0];
    const float* gate_w  = (const float*)d_in[1];
    const float* gate_b  = (const float*)d_in[2];
    const float* value_w = (const float*)d_in[3];
    const float* geom_w  = (const float*)d_in[4];
    const float* geom_b  = (const float*)d_in[5];
    const float* pw_w    = (const float*)d_in[6];
    const float* pw_b    = (const float*)d_in[7];
    float* out = (float*)d_out;

    float* ws  = (float*)d_ws;
    float* v    = ws;                                  // B*L*64   = 8388608
    float* mu   = v    + (size_t)Bx * Ll * 64;         // B*4*L    = 524288
    float* cs2  = mu   + (size_t)Bx * 4 * Ll;
    float* sn2  = cs2  + (size_t)Bx * 4 * Ll;
    float* bse  = sn2  + (size_t)Bx * 4 * Ll;
    float* hyp  = bse  + (size_t)Bx * 4 * Ll;
    float* wt16 = hyp  + (size_t)Bx * 4 * Ll;                 // 1024 f
    unsigned short* vwb16 = (unsigned short*)(wt16 + 1024);   // 4096 us
    unsigned short* pwb16 = vwb16 + 4096;                     // 16384 us
    // total ws: ~44 MB

    k0_pack_weights<<<1, 256, 0, stream>>>(gate_w, geom_w, value_w, pw_w,
                                           wt16, vwb16, pwb16);
    k1_project<<<NPIX / 64, 256, 0, stream>>>(x, vwb16, wt16, gate_b, geom_b,
                                              v, mu, cs2, sn2, bse, hyp);
    k23_fused<<<NPIX / TP, 256, 0, stream>>>(mu, cs2, sn2, bse, hyp,
                                             v, pwb16, pw_b, out);
}

// Round 12
// 75.262 us; speedup vs baseline: 2.1818x; 1.1503x over previous
//
#include <hip/hip_runtime.h>

namespace {
constexpr int Bx = 8, Cc = 64, Hh = 128, Ww = 128, Co = 64;
constexpr int Ll = Hh * Ww;        // 16384 = 2^14
constexpr int NPIX = Bx * Ll;      // 131072
constexpr int TP = 64;             // pixels per block in k23
}

using short8 = __attribute__((ext_vector_type(8))) short;
using f32x4  = __attribute__((ext_vector_type(4))) float;

__device__ __forceinline__ unsigned short f32_to_bf16(float f) {
    union { float f; unsigned u; } un; un.f = f;
    unsigned r = un.u + 0x7FFFu + ((un.u >> 16) & 1u);   // round-to-nearest-even
    return (unsigned short)(r >> 16);
}
// packed pair via HW converter (RNE); no builtin on gfx950 -> inline asm
__device__ __forceinline__ unsigned cvt_pk_bf16(float lo, float hi) {
    unsigned u;
    asm("v_cvt_pk_bf16_f32 %0, %1, %2" : "=v"(u) : "v"(lo), "v"(hi));
    return u;
}
__device__ __forceinline__ float bflo(unsigned u) {
    union { unsigned x; float f; } c; c.x = u << 16; return c.f;
}
__device__ __forceinline__ float bfhi(unsigned u) {
    union { unsigned x; float f; } c; c.x = u & 0xFFFF0000u; return c.f;
}

// ---------------- k0: pack weights ----------------
// wt16 [c][16] fp32: gate(4) + geom(12) — k1's scalar path (fp32 required:
// the theta half-angle math is chaotically sensitive; bf16 there fails).
// vwb16: value_w as MFMA A-frags (single bf16), [t=4][ks=2][lane=64][jj=8].
// pwb16 k-order m' = c*4+r (matches k23's packed agg writes).
__global__ __launch_bounds__(256) void k0_pack_weights(
    const float* __restrict__ gate_w,   // [4][64]
    const float* __restrict__ geom_w,   // [12][64]
    const float* __restrict__ value_w,  // [64][64]
    const float* __restrict__ pw_w,     // [64][256], m = r*64+c
    float* __restrict__ wt16,           // [64][16]
    unsigned short* __restrict__ vwb16, // [4096]
    unsigned short* __restrict__ pwb16) // [64][256] bf16, m' = c*4+r
{
    for (int idx = threadIdx.x; idx < Cc * 16; idx += 256) {
        const int c = idx >> 4, j = idx & 15;
        wt16[idx] = (j < 4) ? gate_w[j * Cc + c] : geom_w[(j - 4) * Cc + c];
    }
    for (int flat = threadIdx.x; flat < 4096; flat += 256) {
        const int t    = flat >> 10;
        const int ks   = (flat >> 9) & 1;
        const int lane = (flat >> 3) & 63;
        const int jj   = flat & 7;
        const int j = t * 16 + (lane & 15);
        const int c = ks * 32 + ((lane >> 4) & 3) * 8 + jj;
        vwb16[flat] = f32_to_bf16(value_w[j * Cc + c]);
    }
    for (int idx = threadIdx.x; idx < Co * 256; idx += 256) {
        const int o = idx >> 8, m = idx & 255;
        const int r = m >> 6, c = m & 63;
        pwb16[o * 256 + c * 4 + r] = f32_to_bf16(pw_w[idx]);
    }
}

__device__ __forceinline__ float softplusf(float v) {
    return v > 20.f ? v : log1pf(__expf(v));
}

// ---------------- k1: hybrid projections, 64 px/block (grid 2048) ----------------
// 4 threads share a pixel: thread (ch=tid>>6, px=tid&63) loads its 16 x
// channels (coalesced in px), stages bf16 to LDS (cvt_pk), accumulates PARTIAL
// fp32 gate/geom sums; partials reduced through LDS. Epilogue distributed:
// wave g handles {softmax | sincos | base | hyper}. Value channels via bf16
// MFMA: wave ch owns p-tile ch (16 px), 8 MFMAs.
__global__ __launch_bounds__(256) void k1_project(
    const float* __restrict__ x,       // [B][64][L]
    const unsigned short* __restrict__ vwb16,
    const float* __restrict__ wt16,    // [64][16]
    const float* __restrict__ gate_b,  // [4]
    const float* __restrict__ geom_b,  // [12]
    float* __restrict__ v,             // [B][L][64]  (pixel-major)
    float* __restrict__ mu,            // [B][4][L]
    float* __restrict__ cs2, float* __restrict__ sn2,
    float* __restrict__ bse, float* __restrict__ hyp)  // each [B][4][L]
{
    __shared__ unsigned short xb16[64][72];   // 9,216 B
    __shared__ float part[4][64][17];         // 17,408 B; total 26.6 KB

    const int tid  = threadIdx.x;
    const int px   = tid & 63;
    const int ch   = tid >> 6;               // channel-quarter / wave id
    const int lane = tid & 63;
    const int pix0 = blockIdx.x * 64;
    const int b    = pix0 >> 14;
    const int l0   = pix0 & (Ll - 1);

    // stage my 16 channels + partial gate/geom accumulation
    float acc[16];
#pragma unroll
    for (int j = 0; j < 16; ++j) acc[j] = 0.f;

    const float* xb = x + (size_t)b * Cc * Ll + (l0 + px);
#pragma unroll
    for (int j0 = 0; j0 < 16; j0 += 8) {
        float xv[8];
#pragma unroll
        for (int j = 0; j < 8; ++j) xv[j] = xb[(size_t)(ch * 16 + j0 + j) * Ll];
        uint4 ph;
        unsigned* hp = (unsigned*)&ph;
#pragma unroll
        for (int j = 0; j < 4; ++j)
            hp[j] = cvt_pk_bf16(xv[2 * j], xv[2 * j + 1]);
        *(uint4*)&xb16[px][ch * 16 + j0] = ph;
#pragma unroll
        for (int j = 0; j < 8; ++j) {
            const float* wr = wt16 + (ch * 16 + j0 + j) * 16;   // uniform
#pragma unroll
            for (int jj = 0; jj < 16; ++jj) acc[jj] = fmaf(wr[jj], xv[j], acc[jj]);
        }
    }
#pragma unroll
    for (int jj = 0; jj < 16; ++jj) part[ch][px][jj] = acc[jj];

    // A fragments (value weights) — issue early, consumed after barrier
    short8 af[8];
#pragma unroll
    for (int i = 0; i < 8; ++i)
        af[i] = *(const short8*)(vwb16 + ((size_t)(i * 64 + lane)) * 8);

    __syncthreads();

    // distributed epilogue: wave g handles output group g for all 64 px
    {
        const int g = ch;
        const int l = l0 + px;
        const size_t fb = (size_t)b * 4 * Ll + l;
        float o[4];
#pragma unroll
        for (int q = 0; q < 4; ++q)
            o[q] = part[0][px][4 * g + q] + part[1][px][4 * g + q]
                 + part[2][px][4 * g + q] + part[3][px][4 * g + q];
        if (g == 0) {
            float e[4], gm = -1e30f;
#pragma unroll
            for (int q = 0; q < 4; ++q) { e[q] = o[q] + gate_b[q]; gm = fmaxf(gm, e[q]); }
            float gs = 0.f;
#pragma unroll
            for (int q = 0; q < 4; ++q) { e[q] = __expf(e[q] - gm); gs += e[q]; }
            const float gi = __fdividef(1.f, gs);
#pragma unroll
            for (int q = 0; q < 4; ++q) mu[fb + (size_t)q * Ll] = e[q] * gi;
        } else if (g == 1) {
#pragma unroll
            for (int q = 0; q < 4; ++q) {
                float sv, cv;
                __sincosf(2.f * (o[q] + geom_b[q]), &sv, &cv);
                cs2[fb + (size_t)q * Ll] = cv;
                sn2[fb + (size_t)q * Ll] = sv;
            }
        } else if (g == 2) {
#pragma unroll
            for (int q = 0; q < 4; ++q)
                bse[fb + (size_t)q * Ll] = softplusf(o[q] + geom_b[4 + q]) + 1e-4f;
        } else {
#pragma unroll
            for (int q = 0; q < 4; ++q)
                hyp[fb + (size_t)q * Ll] = softplusf(o[q] + geom_b[8 + q]);
        }
    }

    // value channels via single-bf16 MFMA: wave ch owns p-tile ch
    const int px16 = lane & 15;
    const int g2   = lane >> 4;
    {
        const int row = ch * 16 + px16;
        const short8 bh0 = *(const short8*)&xb16[row][g2 * 8];
        const short8 bh1 = *(const short8*)&xb16[row][32 + g2 * 8];

        f32x4 d0, d1, d2, d3;
#define PROJ_TILE(dst, t)                                              \
        {                                                              \
            f32x4 a_ = {0.f, 0.f, 0.f, 0.f};                           \
            a_ = __builtin_amdgcn_mfma_f32_16x16x32_bf16(af[2*(t)],   bh0, a_, 0, 0, 0); \
            a_ = __builtin_amdgcn_mfma_f32_16x16x32_bf16(af[2*(t)+1], bh1, a_, 0, 0, 0); \
            dst = a_;                                                  \
        }
        PROJ_TILE(d0, 0) PROJ_TILE(d1, 1) PROJ_TILE(d2, 2) PROJ_TILE(d3, 3)
#undef PROJ_TILE

        const int l = l0 + ch * 16 + px16;
        float* vrow = v + ((size_t)b * Ll + l) * 64 + g2 * 4;
        *(f32x4*)(vrow)      = d0;
        *(f32x4*)(vrow + 16) = d1;
        *(f32x4*)(vrow + 32) = d2;
        *(f32x4*)(vrow + 48) = d3;
    }
}

// ---------------- k23: fused compat + aggregation + MFMA pointwise ----------------
// TP=64 pixels, 256 threads = 4 waves. LDS 39936 B -> 4 blocks/CU.
// XCD-bijective block swizzle (2048 %% 8 == 0): each XCD owns one contiguous
// batch image, so +-1-row field-halo re-reads hit the local L2.
// Stage A (lane=pixel): thread (px, r=wave) computes 9 normalized compat
// weights -> packed bf16 pairs in LDS wqpk[r][px][6] (b64-aligned rows).
// Stage B (lane=channel): wave w owns px w*16..+15; 54 hoisted v-lines;
// wq via uniform b64 broadcasts + 1-inst unpack; agg packed via cvt_pk.
// Stage C: wave w -> o-tile w*16; A-frags pre-barrier; 4 p-tiles, bias C-init.
__global__ __launch_bounds__(256, 4) void k23_fused(
    const float* __restrict__ mu,
    const float* __restrict__ cs2, const float* __restrict__ sn2,
    const float* __restrict__ bse, const float* __restrict__ hyp,
    const float* __restrict__ v,             // [B][L][64]
    const unsigned short* __restrict__ pwb16,// [64][256] bf16, m'-order
    const float* __restrict__ pw_b,          // [64]
    float* __restrict__ out)                 // [B][64][L]
{
    __shared__ unsigned wqpk[4][64][6];      // 6,144 B (bf16 pairs, 9 used/12)
    __shared__ unsigned short agg[TP][264];  // 33,792 B

    const int tid = threadIdx.x;
    const int cpx = (int)(gridDim.x >> 3);   // 256
    const int bid = (int)((blockIdx.x & 7) * cpx + (blockIdx.x >> 3));
    const int pix0 = bid * TP;
    const int b = pix0 >> 14;
    const int l0 = pix0 & (Ll - 1);

    // ---- stage A: lane = pixel ----
    {
        const int px = tid & 63;
        const int r  = tid >> 6;
        const int l  = l0 + px;
        const int hr = l >> 7;
        const int wc = l & (Ww - 1);
        const size_t fb = ((size_t)b * 4 + r) * Ll;

        const float cc = cs2[fb + l], sc = sn2[fb + l];
        const float bc = bse[fb + l], yc = hyp[fb + l];
        const float mc = mu[fb + l];

        float cmp[9];
        float sum = 0.f;
#pragma unroll
        for (int s = 0; s < 9; ++s) {
            const int dy = s / 3 - 1, dx = s % 3 - 1;
            float cv;
            if (dx == 0 && dy == 0) {
                cv = mc;
            } else {
                const int hh = hr + dy, ww = wc + dx;
                const int hcl = min(max(hh, 0), Hh - 1);
                const int wcl = min(max(ww, 0), Ww - 1);
                const bool inb = ((unsigned)hh < (unsigned)Hh) &
                                 ((unsigned)ww < (unsigned)Ww);
                const size_t ni = fb + hcl * Ww + wcl;
                const float cn = cs2[ni], sn = sn2[ni];
                const float bn = bse[ni], yn = hyp[ni];
                const float mun = inb ? mu[ni] : 0.f;
                const float c2 = cc + cn, s2 = sc + sn;
                const float h = sqrtf(fmaxf(c2 * c2 + s2 * s2, 1e-24f));
                const float rh = __fdividef(0.5f, h);
                float pu2, ps2;
                if (dx != 0 && dy != 0) {              // diagonal
                    const float t = 2.f * (float)(dx * dy) * (s2 * rh);
                    pu2 = 1.f + t; ps2 = 1.f - t;
                } else if (dx != 0) {                  // horizontal
                    pu2 = 0.5f + c2 * rh; ps2 = 0.5f - c2 * rh;
                } else {                               // vertical
                    pu2 = 0.5f - c2 * rh; ps2 = 0.5f + c2 * rh;
                }
                const float bp = 0.5f * (bc + bn);
                const float hp = 0.5f * (yc + yn);
                const float E = __expf(hp);
                const float iu = __fdividef(1.f, bp * E);   // 1/sigma_u
                const float is = E * E * iu;                // 1/sigma_s
                const float q = pu2 * (iu * iu) + ps2 * (is * is);
                cv = __expf(-q) * mun;
            }
            cmp[s] = cv;
            sum += cv;
        }
        const float inv = __fdividef(1.f, sum + 1e-6f);
        unsigned* wrow = &wqpk[r][px][0];
#pragma unroll
        for (int k = 0; k < 4; ++k)
            wrow[k] = cvt_pk_bf16(cmp[2 * k] * inv, cmp[2 * k + 1] * inv);
        wrow[4] = cvt_pk_bf16(cmp[8] * inv, 0.f);
    }
    __syncthreads();

    // ---- stage B: lane = channel ----
    const int w = tid >> 6, c = tid & 63;
    {
        const int hr0  = l0 >> 7;
        const int rows[3] = { max(hr0 - 1, 0) * Ww, hr0 * Ww, min(hr0 + 1, Hh - 1) * Ww };
        const int colbase = (l0 & (Ww - 1)) + w * 16;
        const float* vb = v + ((size_t)b * Ll) * 64 + c;

        float vv[3][18];
#pragma unroll
        for (int ry = 0; ry < 3; ++ry)
#pragma unroll
            for (int cx = 0; cx < 18; ++cx) {
                const int col = min(max(colbase + cx - 1, 0), Ww - 1);
                vv[ry][cx] = vb[(size_t)(rows[ry] + col) * 64];
            }

#pragma unroll
        for (int p = 0; p < 16; ++p) {
            float av[4];
#pragma unroll
            for (int r = 0; r < 4; ++r) {
                const unsigned* wrow = &wqpk[r][w * 16 + p][0];
                const unsigned u0 = wrow[0], u1 = wrow[1], u2 = wrow[2],
                               u3 = wrow[3], u4 = wrow[4];
                float a;
                a = bflo(u0) * vv[0][p];
                a = fmaf(bfhi(u0), vv[0][p + 1], a);
                a = fmaf(bflo(u1), vv[0][p + 2], a);
                a = fmaf(bfhi(u1), vv[1][p],     a);
                a = fmaf(bflo(u2), vv[1][p + 1], a);
                a = fmaf(bfhi(u2), vv[1][p + 2], a);
                a = fmaf(bflo(u3), vv[2][p],     a);
                a = fmaf(bfhi(u3), vv[2][p + 1], a);
                a = fmaf(bflo(u4), vv[2][p + 2], a);
                av[r] = a;
            }
            uint2 u;
            u.x = cvt_pk_bf16(av[0], av[1]);
            u.y = cvt_pk_bf16(av[2], av[3]);
            *((uint2*)(&agg[w * 16 + p][0]) + c) = u;   // m' = c*4+r
        }
    }

    // A fragments: issue before the barrier (in flight across it)
    const int ar    = tid & 15;
    const int chunk = (tid >> 4) & 3;
    const int o0    = w * 16;
    const unsigned short* aPtr = pwb16 + (o0 + ar) * 256 + chunk * 8;
    short8 af[8];
#pragma unroll
    for (int kt = 0; kt < 8; ++kt) af[kt] = *(const short8*)(aPtr + kt * 32);

    __syncthreads();

    // ---- stage C: MFMA pointwise, 4 p-tiles, A reused ----
    f32x4 d0, d1, d2, d3;
#pragma unroll
    for (int q = 0; q < 4; ++q) {
        const float bv = pw_b[o0 + chunk * 4 + q];
        d0[q] = bv; d1[q] = bv; d2[q] = bv; d3[q] = bv;
    }
    const unsigned short* b0 = &agg[ 0 + ar][chunk * 8];
    const unsigned short* b1 = &agg[16 + ar][chunk * 8];
    const unsigned short* b2 = &agg[32 + ar][chunk * 8];
    const unsigned short* b3 = &agg[48 + ar][chunk * 8];
#pragma unroll
    for (int kt = 0; kt < 8; ++kt) {
        d0 = __builtin_amdgcn_mfma_f32_16x16x32_bf16(af[kt], *(const short8*)(b0 + kt * 32), d0, 0, 0, 0);
        d1 = __builtin_amdgcn_mfma_f32_16x16x32_bf16(af[kt], *(const short8*)(b1 + kt * 32), d1, 0, 0, 0);
        d2 = __builtin_amdgcn_mfma_f32_16x16x32_bf16(af[kt], *(const short8*)(b2 + kt * 32), d2, 0, 0, 0);
        d3 = __builtin_amdgcn_mfma_f32_16x16x32_bf16(af[kt], *(const short8*)(b3 + kt * 32), d3, 0, 0, 0);
    }

#pragma unroll
    for (int q = 0; q < 4; ++q) {
        const int o = o0 + chunk * 4 + q;
        float* ob = out + ((size_t)b * Co + o) * Ll + l0 + ar;
        ob[0]  = d0[q];
        ob[16] = d1[q];
        ob[32] = d2[q];
        ob[48] = d3[q];
    }
}

// ---------------- launch ----------------
extern "C" void kernel_launch(void* const* d_in, const int* in_sizes, int n_in,
                              void* d_out, int out_size, void* d_ws, size_t ws_size,
                              hipStream_t stream)
{
    const float* x       = (const float*)d_in[0];
    const float* gate_w  = (const float*)d_in[1];
    const float* gate_b  = (const float*)d_in[2];
    const float* value_w = (const float*)d_in[3];
    const float* geom_w  = (const float*)d_in[4];
    const float* geom_b  = (const float*)d_in[5];
    const float* pw_w    = (const float*)d_in[6];
    const float* pw_b    = (const float*)d_in[7];
    float* out = (float*)d_out;

    float* ws  = (float*)d_ws;
    float* v    = ws;                                  // B*L*64   = 8388608
    float* mu   = v    + (size_t)Bx * Ll * 64;         // B*4*L    = 524288
    float* cs2  = mu   + (size_t)Bx * 4 * Ll;
    float* sn2  = cs2  + (size_t)Bx * 4 * Ll;
    float* bse  = sn2  + (size_t)Bx * 4 * Ll;
    float* hyp  = bse  + (size_t)Bx * 4 * Ll;
    float* wt16 = hyp  + (size_t)Bx * 4 * Ll;                 // 1024 f
    unsigned short* vwb16 = (unsigned short*)(wt16 + 1024);   // 4096 us
    unsigned short* pwb16 = vwb16 + 4096;                     // 16384 us
    // total ws: ~44 MB

    k0_pack_weights<<<1, 256, 0, stream>>>(gate_w, geom_w, value_w, pw_w,
                                           wt16, vwb16, pwb16);
    k1_project<<<NPIX / 64, 256, 0, stream>>>(x, vwb16, wt16, gate_b, geom_b,
                                              v, mu, cs2, sn2, bse, hyp);
    k23_fused<<<NPIX / TP, 256, 0, stream>>>(mu, cs2, sn2, bse, hyp,
                                             v, pwb16, pw_b, out);
}